// Round 4
// baseline (447.415 us; speedup 1.0000x reference)
//
#include <hip/hip_runtime.h>
#include <math.h>

#define HIDDEN 2048
#define NEXP   64
#define BK     64            // k-chunk staged in LDS
#define NCHUNK (HIDDEN/BK)   // 32
#define TPB    512           // 8 waves
#define NW     8             // waves = expert groups
#define TOKB   32            // tokens per block
#define EW     8             // experts per wave
#define TJ     8             // tokens per lane (per quarter-group)

typedef __attribute__((address_space(3))) unsigned int       lds_u32;
typedef __attribute__((address_space(1))) const unsigned int gbl_u32;

// rotate-reduce step over rows of 16 lanes, on the VALU pipe (DPP), not LDS.
// ROW_ROR:N = 0x120|N. Sum over rotations 1,2,4,8 -> all 16 lanes hold the sum.
template<int CTRL>
__device__ __forceinline__ float ror_add(float v) {
  int r = __builtin_amdgcn_update_dpp(0, __float_as_int(v), CTRL, 0xF, 0xF, true);
  return v + __int_as_float(r);
}

__global__ __launch_bounds__(TPB, 4)
void router_kernel(const float* __restrict__ x,
                   const float* __restrict__ Wg,
                   const float* __restrict__ gb,
                   float* __restrict__ out, int T)
{
  // xt: [tok 32][k 64] f32 — quarter-wave (16 lanes) reads one 256B token row:
  //     same bank profile as lane-linear b128 = conflict-free.
  // wt: [exp 64][k 64] f32 — 16 distinct 16B slots x 4-way same-addr: free.
  __shared__ float xt[2][TOKB * BK];      // 16 KB
  __shared__ float wt[2][NEXP * BK];      // 32 KB
  __shared__ float sc[NW][TOKB][4];       // 4 KB: per-group top-2 candidates

  const int tid  = threadIdx.x;
  const int lane = tid & 63;
  const int wv   = tid >> 6;        // expert group 0..7
  const int e0   = wv * EW;
  const int q    = lane >> 4;       // token quarter 0..3
  const int m    = lane & 15;       // k-slice 0..15 (4 floats each)
  const int tokB = (int)blockIdx.x * TOKB;

  float acc[TJ][EW];                // 64 accumulators, fully static-indexed
#pragma unroll
  for (int t = 0; t < TJ; ++t)
#pragma unroll
    for (int e = 0; e < EW; ++e) acc[t][e] = 0.f;

  auto stage = [&](int buf, int k0) {
    // x tile: 512 thr x 16B = 8KB, dest linear (addr = tid*16)
    {
      const int tk = tid >> 4, kw = tid & 15;
      __builtin_amdgcn_global_load_lds(
          (gbl_u32*)&x[(size_t)(tokB + tk) * HIDDEN + k0 + 4 * kw],
          (lds_u32*)&xt[buf][tk * BK + 4 * kw], 16, 0, 0);
    }
    // W tile: 1024 slots x 16B = 16KB, dest linear per wave
#pragma unroll
    for (int j = 0; j < 2; ++j) {
      const int s = j * TPB + tid;
      const int e = s >> 4, kw = s & 15;
      __builtin_amdgcn_global_load_lds(
          (gbl_u32*)&Wg[(size_t)e * HIDDEN + k0 + 4 * kw],
          (lds_u32*)&wt[buf][e * BK + 4 * kw], 16, 0, 0);
    }
  };

  stage(0, 0);
  __syncthreads();

  int cur = 0;
  for (int c = 0; c < NCHUNK; ++c) {
    if (c + 1 < NCHUNK) stage(cur ^ 1, (c + 1) * BK);

    // preload this wave's 8 expert slices (reused by all 8 tokens)
    float4 wr[EW];
#pragma unroll
    for (int e = 0; e < EW; ++e)
      wr[e] = *(const float4*)&wt[cur][(e0 + e) * BK + 4 * m];

#pragma unroll
    for (int tj = 0; tj < TJ; ++tj) {
      const float4 xv = *(const float4*)&xt[cur][(q * TJ + tj) * BK + 4 * m];
#pragma unroll
      for (int e = 0; e < EW; ++e) {
        acc[tj][e] = fmaf(xv.x, wr[e].x, acc[tj][e]);
        acc[tj][e] = fmaf(xv.y, wr[e].y, acc[tj][e]);
        acc[tj][e] = fmaf(xv.z, wr[e].z, acc[tj][e]);
        acc[tj][e] = fmaf(xv.w, wr[e].w, acc[tj][e]);
      }
    }

    __syncthreads();    // drains staging vmcnt + orders buffer reuse
    cur ^= 1;
  }

  // ---- k-slice reduce over the 16 m-lanes (VALU/DPP, not LDS) ----
#pragma unroll
  for (int tj = 0; tj < TJ; ++tj)
#pragma unroll
    for (int e = 0; e < EW; ++e) {
      float v = acc[tj][e];
      v = ror_add<0x121>(v);   // ror 1
      v = ror_add<0x122>(v);   // ror 2
      v = ror_add<0x124>(v);   // ror 4
      v = ror_add<0x128>(v);   // ror 8
      acc[tj][e] = v;          // all 16 lanes of the row hold the full sum
    }

  // ---- per-group (8 experts) top-2 per token, bias added ----
  float bias[EW];
#pragma unroll
  for (int e = 0; e < EW; ++e) bias[e] = gb[e0 + e];

#pragma unroll
  for (int tj = 0; tj < TJ; ++tj) {
    float b1 = acc[tj][0] + bias[0], b2 = -3.402823466e+38f;
    int   i1 = e0, i2 = e0;
#pragma unroll
    for (int e = 1; e < EW; ++e) {
      const float v = acc[tj][e] + bias[e];
      if (v > b1)      { b2 = b1; i2 = i1; b1 = v; i1 = e0 + e; }
      else if (v > b2) { b2 = v;  i2 = e0 + e; }
    }
    if (m == 0) {
      sc[wv][q * TJ + tj][0] = b1;
      sc[wv][q * TJ + tj][1] = (float)i1;
      sc[wv][q * TJ + tj][2] = b2;
      sc[wv][q * TJ + tj][3] = (float)i2;
    }
  }
  __syncthreads();

  // ---- combine 8 groups' candidates; groups ascending => tie -> lower idx ----
  if (tid < TOKB) {
    float b1 = -3.402823466e+38f, b2 = -3.402823466e+38f;
    float i1 = 0.f, i2 = 0.f;
#pragma unroll
    for (int g = 0; g < NW; ++g) {
      const float4 cnd = *(const float4*)&sc[g][tid][0];
      if (cnd.x > b1)      { b2 = b1; i2 = i1; b1 = cnd.x; i1 = cnd.y; }
      else if (cnd.x > b2) { b2 = cnd.x; i2 = cnd.y; }
      if (cnd.z > b1)      { b2 = b1; i2 = i1; b1 = cnd.z; i1 = cnd.w; }
      else if (cnd.z > b2) { b2 = cnd.z; i2 = cnd.w; }
    }
    const int tok = tokB + tid;
    const float e2 = expf(b2 - b1);
    const float s  = 1.f / (1.f + e2);
    out[2 * tok]     = s;            // weights, descending like top_k
    out[2 * tok + 1] = e2 * s;
    out[2 * T + 2 * tok]     = i1;   // idx section (float-encoded)
    out[2 * T + 2 * tok + 1] = i2;
  }
}

extern "C" void kernel_launch(void* const* d_in, const int* in_sizes, int n_in,
                              void* d_out, int out_size, void* d_ws, size_t ws_size,
                              hipStream_t stream) {
  const float* x  = (const float*)d_in[0];   // [4,8192,2048] f32
  const float* Wg = (const float*)d_in[1];   // [64,2048] f32
  const float* gb = (const float*)d_in[2];   // [64] f32
  float* out = (float*)d_out;                // [2*T weights][2*T idx-as-float]
  const int T = in_sizes[0] / HIDDEN;        // 32768 tokens
  router_kernel<<<dim3(T / TOKB), dim3(TPB), 0, stream>>>(x, Wg, gb, out, T);
}

// Round 5
// 100.524 us; speedup vs baseline: 4.4508x; 4.4508x over previous
//
#include <hip/hip_runtime.h>
#include <math.h>

#define HIDDEN 2048
#define NEXP   64
#define KSTEPS (HIDDEN/32)    // 64 MFMA k-steps
#define NT     4              // four 16-expert N-tiles
#define WS_HALVES (KSTEPS*NT*2*64*8)   // 262144 halves = 512 KB

typedef _Float16 f16x8 __attribute__((ext_vector_type(8)));
typedef float    f32x4 __attribute__((ext_vector_type(4)));

// ---------------- prep: W -> split-f16 MFMA B-fragments in ws ----------------
// ws layout: [ks][nt][split][lane][8 halves]; offset = (ks*4+nt)*1024 + split*512 + lane*8
// B-frag mapping (16x16x32): col(expert) = lane&15, k = 8*(lane>>4)+j
__global__ void prep_w(const float* __restrict__ Wg, _Float16* __restrict__ ws) {
  const int t    = blockIdx.x * 256 + threadIdx.x;  // 0..16383 = grp*64 + lane
  const int lane = t & 63;
  const int grp  = t >> 6;                          // ks*4 + nt
  const int e    = (grp & 3) * 16 + (lane & 15);
  const int k0   = (grp >> 2) * 32 + (lane >> 4) * 8;
  const float* src = &Wg[(size_t)e * HIDDEN + k0];
  f16x8 h, l;
#pragma unroll
  for (int j = 0; j < 8; ++j) {
    const float v = src[j];
    const _Float16 hh = (_Float16)v;        // RNE
    h[j] = hh;
    l[j] = (_Float16)(v - (float)hh);       // exact residual, RNE to f16
  }
  *(f16x8*)&ws[(size_t)grp * 1024 + 0   + lane * 8] = h;
  *(f16x8*)&ws[(size_t)grp * 1024 + 512 + lane * 8] = l;
}

// ---------------- main: MFMA split-f16 router, no LDS, no barriers ----------------
__global__ __launch_bounds__(256, 2)   // 256-VGPR budget: no spill
void router_mfma(const float* __restrict__ x, const _Float16* __restrict__ ws,
                 const float* __restrict__ gb, float* __restrict__ out, int T)
{
  const int tid  = threadIdx.x;
  const int lane = tid & 63;
  const int tok0 = ((int)blockIdx.x * 4 + (tid >> 6)) * 16;
  // A-frag: row(token) = lane&15, k = 8*(lane>>4)+j  (8 contiguous fp32 per lane)
  const float* xp = &x[(size_t)(tok0 + (lane & 15)) * HIDDEN + (lane >> 4) * 8];

  f32x4 acch[NT], accl[NT];
#pragma unroll
  for (int nt = 0; nt < NT; ++nt)
#pragma unroll
    for (int j = 0; j < 4; ++j) { acch[nt][j] = 0.f; accl[nt][j] = 0.f; }

#pragma unroll 2
  for (int ks = 0; ks < KSTEPS; ++ks) {
    const float4 xa = *(const float4*)(xp + ks * 32);
    const float4 xb = *(const float4*)(xp + ks * 32 + 4);
    const float xs[8] = {xa.x, xa.y, xa.z, xa.w, xb.x, xb.y, xb.z, xb.w};
    f16x8 ah, al;
#pragma unroll
    for (int j = 0; j < 8; ++j) {
      const _Float16 h = (_Float16)xs[j];
      ah[j] = h;
      al[j] = (_Float16)(xs[j] - (float)h);
    }
    const _Float16* wp = &ws[(size_t)ks * 4096 + lane * 8];
#pragma unroll
    for (int nt = 0; nt < NT; ++nt) {
      const f16x8 bh = *(const f16x8*)(wp + nt * 1024);
      const f16x8 bl = *(const f16x8*)(wp + nt * 1024 + 512);
      acch[nt] = __builtin_amdgcn_mfma_f32_16x16x32_f16(ah, bh, acch[nt], 0, 0, 0);
      accl[nt] = __builtin_amdgcn_mfma_f32_16x16x32_f16(ah, bl, accl[nt], 0, 0, 0);
      accl[nt] = __builtin_amdgcn_mfma_f32_16x16x32_f16(al, bh, accl[nt], 0, 0, 0);
    }
  }

  // ---- epilogue: C/D row(token)=(lane>>4)*4+reg, col(expert)=lane&15 [m89] ----
  float bias[NT];
#pragma unroll
  for (int nt = 0; nt < NT; ++nt) bias[nt] = gb[nt * 16 + (lane & 15)];

  const int q = lane >> 4;
#pragma unroll
  for (int r = 0; r < 4; ++r) {
    float v1 = acch[0][r] + accl[0][r] + bias[0];
    int   i1 = lane & 15;
    float v2 = -3.402823466e+38f;
    int   i2 = i1;
#pragma unroll
    for (int nt = 1; nt < NT; ++nt) {
      const float v = acch[nt][r] + accl[nt][r] + bias[nt];
      const int  ie = nt * 16 + (lane & 15);
      if (v > v1)      { v2 = v1; i2 = i1; v1 = v; i1 = ie; }
      else if (v > v2) { v2 = v;  i2 = ie; }
    }
    // top-2 merge across the 16 lanes of this quarter (they hold this token's experts)
#pragma unroll
    for (int m = 1; m <= 8; m <<= 1) {
      const float o1 = __shfl_xor(v1, m, 64); const int oi1 = __shfl_xor(i1, m, 64);
      const float o2 = __shfl_xor(v2, m, 64); const int oi2 = __shfl_xor(i2, m, 64);
      const bool b = (o1 > v1) || (o1 == v1 && oi1 < i1);
      if (b) {
        const bool c = (v1 > o2) || (v1 == o2 && i1 < oi2);
        v2 = c ? v1 : o2; i2 = c ? i1 : oi2;
        v1 = o1; i1 = oi1;
      } else {
        const bool c = (o1 > v2) || (o1 == v2 && oi1 < i2);
        if (c) { v2 = o1; i2 = oi1; }
      }
    }
    if ((lane & 15) == 0) {
      const int tok = tok0 + q * 4 + r;
      const float e2 = expf(v2 - v1);
      const float s  = 1.f / (1.f + e2);
      out[2 * tok]     = s;                 // weights, descending like top_k
      out[2 * tok + 1] = e2 * s;
      out[2 * T + 2 * tok]     = (float)i1; // idx section (float-encoded)
      out[2 * T + 2 * tok + 1] = (float)i2;
    }
  }
}

// ---------------- fallback (proven R2 kernel) if ws too small ----------------
#define BK 64
#define NK4 (BK/4)
#define NCHUNK (HIDDEN/BK)
#define TPB 512
#define NWAVE 8
#define TPW 8
#define TPBK 64
typedef __attribute__((address_space(3))) unsigned int       lds_u32;
typedef __attribute__((address_space(1))) const unsigned int gbl_u32;

__global__ __launch_bounds__(TPB, 4)
void router_fb(const float* __restrict__ x, const float* __restrict__ Wg,
               const float* __restrict__ gb, float* __restrict__ out, int T)
{
  __shared__ float4 wlds[2][NK4][NEXP];
  __shared__ float4 xlds[2][NWAVE][TPW][NK4];
  const int tid = threadIdx.x, lane = tid & 63, wid = tid >> 6;
  const int tok0 = (int)blockIdx.x * TPBK + wid * TPW;
  float acc[TPW]; double dacc[TPW];
#pragma unroll
  for (int t = 0; t < TPW; ++t) { acc[t] = 0.f; dacc[t] = 0.0; }
  auto stageW = [&](int buf, int k0) {
#pragma unroll
    for (int j = 0; j < 2; ++j) {
      const int s = tid + j * TPB, e = s & 63, k4 = s >> 6;
      __builtin_amdgcn_global_load_lds((gbl_u32*)&Wg[(size_t)e * HIDDEN + k0 + 4 * k4],
                                       (lds_u32*)&wlds[buf][k4][e], 16, 0, 0);
    }
  };
  auto stageX = [&](int buf, int k0) {
#pragma unroll
    for (int j = 0; j < 2; ++j) {
      const int s = lane + j * 64, t = s >> 4, k4 = s & 15;
      __builtin_amdgcn_global_load_lds((gbl_u32*)&x[(size_t)(tok0 + t) * HIDDEN + k0 + 4 * k4],
                                       (lds_u32*)&xlds[buf][wid][t][k4], 16, 0, 0);
    }
  };
  stageW(0, 0); stageX(0, 0); __syncthreads();
  int cur = 0;
  for (int c = 0; c < NCHUNK; ++c) {
    if (c + 1 < NCHUNK) { stageW(cur ^ 1, (c + 1) * BK); stageX(cur ^ 1, (c + 1) * BK); }
#pragma unroll
    for (int k4 = 0; k4 < NK4; ++k4) {
      const float4 w = wlds[cur][k4][lane];
#pragma unroll
      for (int t = 0; t < TPW; ++t) {
        const float4 xv = xlds[cur][wid][t][k4];
        acc[t] = fmaf(xv.x, w.x, acc[t]); acc[t] = fmaf(xv.y, w.y, acc[t]);
        acc[t] = fmaf(xv.z, w.z, acc[t]); acc[t] = fmaf(xv.w, w.w, acc[t]);
      }
    }
#pragma unroll
    for (int t = 0; t < TPW; ++t) { dacc[t] += (double)acc[t]; acc[t] = 0.f; }
    __syncthreads(); cur ^= 1;
  }
  const float bv = gb[lane];
#pragma unroll
  for (int t = 0; t < TPW; ++t) {
    const float v = (float)dacc[t] + bv;
    float v1 = v; int i1 = lane;
#pragma unroll
    for (int off = 32; off >= 1; off >>= 1) {
      const float ov = __shfl_xor(v1, off, 64); const int oi = __shfl_xor(i1, off, 64);
      if (ov > v1 || (ov == v1 && oi < i1)) { v1 = ov; i1 = oi; }
    }
    float v2 = (lane == i1) ? -3.402823466e+38f : v; int i2 = lane;
#pragma unroll
    for (int off = 32; off >= 1; off >>= 1) {
      const float ov = __shfl_xor(v2, off, 64); const int oi = __shfl_xor(i2, off, 64);
      if (ov > v2 || (ov == v2 && oi < i2)) { v2 = ov; i2 = oi; }
    }
    if (lane == 0) {
      const int tok = tok0 + t;
      const float e2 = expf(v2 - v1), s = 1.f + e2;
      out[2 * tok] = 1.f / s; out[2 * tok + 1] = e2 / s;
      out[2 * T + 2 * tok] = (float)i1; out[2 * T + 2 * tok + 1] = (float)i2;
    }
  }
}

extern "C" void kernel_launch(void* const* d_in, const int* in_sizes, int n_in,
                              void* d_out, int out_size, void* d_ws, size_t ws_size,
                              hipStream_t stream) {
  const float* x  = (const float*)d_in[0];   // [4,8192,2048] f32
  const float* Wg = (const float*)d_in[1];   // [64,2048] f32
  const float* gb = (const float*)d_in[2];   // [64] f32
  float* out = (float*)d_out;
  const int T = in_sizes[0] / HIDDEN;        // 32768 tokens

  if (ws_size >= WS_HALVES * sizeof(_Float16)) {
    _Float16* ws = (_Float16*)d_ws;
    prep_w<<<dim3(64), dim3(256), 0, stream>>>(Wg, ws);
    router_mfma<<<dim3(T / 64), dim3(256), 0, stream>>>(x, ws, gb, out, T);
  } else {
    router_fb<<<dim3(T / TPBK), dim3(TPB), 0, stream>>>(x, Wg, gb, out, T);
  }
}

// Round 6
// 87.007 us; speedup vs baseline: 5.1423x; 1.1553x over previous
//
#include <hip/hip_runtime.h>
#include <math.h>

#define HIDDEN 2048
#define NEXP   64
#define KSTEPS (HIDDEN/32)    // 64 MFMA k-steps
#define NT     4              // four 16-expert N-tiles
#define WS_HALVES (KSTEPS*NT*2*64*8)   // 262144 halves = 512 KB

typedef _Float16 f16x8 __attribute__((ext_vector_type(8)));
typedef float    f32x4 __attribute__((ext_vector_type(4)));

// ---------------- prep: W -> split-f16 MFMA B-fragments in ws ----------------
// ws layout: [ks][nt][split][lane][8 halves]
// B-frag mapping (16x16x32): col(expert) = lane&15, k = 8*(lane>>4)+j
__global__ void prep_w(const float* __restrict__ Wg, _Float16* __restrict__ ws) {
  const int t    = blockIdx.x * 256 + threadIdx.x;  // 0..16383 = grp*64 + lane
  const int lane = t & 63;
  const int grp  = t >> 6;                          // ks*4 + nt
  const int e    = (grp & 3) * 16 + (lane & 15);
  const int k0   = (grp >> 2) * 32 + (lane >> 4) * 8;
  const float* src = &Wg[(size_t)e * HIDDEN + k0];
  f16x8 h, l;
#pragma unroll
  for (int j = 0; j < 8; ++j) {
    const float v = src[j];
    const _Float16 hh = (_Float16)v;        // RNE
    h[j] = hh;
    l[j] = (_Float16)(v - (float)hh);       // exact residual, RNE to f16
  }
  *(f16x8*)&ws[(size_t)grp * 1024 + 0   + lane * 8] = h;
  *(f16x8*)&ws[(size_t)grp * 1024 + 512 + lane * 8] = l;
}

// ------------- main: MFMA split-f16 router, deep-pipelined loads -------------
__global__ __launch_bounds__(256, 2)   // 256-VGPR budget: no spill
void router_mfma(const float* __restrict__ x, const _Float16* __restrict__ ws,
                 const float* __restrict__ gb, float* __restrict__ out, int T)
{
  const int tid  = threadIdx.x;
  const int lane = tid & 63;
  const int tok0 = ((int)blockIdx.x * 4 + (tid >> 6)) * 16;
  // A-frag: row(token) = lane&15, k = 8*(lane>>4)+j
  const float* xp = &x[(size_t)(tok0 + (lane & 15)) * HIDDEN + (lane >> 4) * 8];
  const _Float16* wsl = ws + lane * 8;

  f32x4 acch[NT], accl[NT];
#pragma unroll
  for (int nt = 0; nt < NT; ++nt)
#pragma unroll
    for (int j = 0; j < 4; ++j) { acch[nt][j] = 0.f; accl[nt][j] = 0.f; }

  // ---- x prefetch pipeline, depth 4 (statically indexed via unroll) ----
  float4 pfa[4], pfb[4];
#pragma unroll
  for (int j = 0; j < 4; ++j) {
    pfa[j] = *(const float4*)(xp + j * 32);
    pfb[j] = *(const float4*)(xp + j * 32 + 4);
  }
  // ---- b-frag double buffer, depth 1 ----
  f16x8 bh[2][NT], bl[2][NT];
#pragma unroll
  for (int nt = 0; nt < NT; ++nt) {
    bh[0][nt] = *(const f16x8*)(wsl + nt * 1024);
    bl[0][nt] = *(const f16x8*)(wsl + nt * 1024 + 512);
  }

  for (int ksb = 0; ksb < KSTEPS; ksb += 4) {
#pragma unroll
    for (int j = 0; j < 4; ++j) {
      const int ks = ksb + j;
      const int cb = j & 1, nb = cb ^ 1;   // ksb%4==0 -> ks&1 == j&1

      // consume x slot j, then immediately refill it for ks+4
      const float4 xa = pfa[j], xb = pfb[j];
      if (ks + 4 < KSTEPS) {
        pfa[j] = *(const float4*)(xp + (ks + 4) * 32);
        pfb[j] = *(const float4*)(xp + (ks + 4) * 32 + 4);
      }
      // issue next k-step's b-frags (L2-hot) before the split VALU work
      if (ks + 1 < KSTEPS) {
        const _Float16* wp = wsl + (size_t)(ks + 1) * 4096;
#pragma unroll
        for (int nt = 0; nt < NT; ++nt) {
          bh[nb][nt] = *(const f16x8*)(wp + nt * 1024);
          bl[nb][nt] = *(const f16x8*)(wp + nt * 1024 + 512);
        }
      }

      // split current x into hi/lo f16 (RNE, residual <= 2^-22) — proven R5 math
      const float xs[8] = {xa.x, xa.y, xa.z, xa.w, xb.x, xb.y, xb.z, xb.w};
      f16x8 ah, al;
#pragma unroll
      for (int q = 0; q < 8; ++q) {
        const _Float16 h = (_Float16)xs[q];
        ah[q] = h;
        al[q] = (_Float16)(xs[q] - (float)h);
      }

#pragma unroll
      for (int nt = 0; nt < NT; ++nt) {
        acch[nt] = __builtin_amdgcn_mfma_f32_16x16x32_f16(ah, bh[cb][nt], acch[nt], 0, 0, 0);
        accl[nt] = __builtin_amdgcn_mfma_f32_16x16x32_f16(ah, bl[cb][nt], accl[nt], 0, 0, 0);
        accl[nt] = __builtin_amdgcn_mfma_f32_16x16x32_f16(al, bh[cb][nt], accl[nt], 0, 0, 0);
      }
    }
  }

  // ---- epilogue: C/D row(token)=(lane>>4)*4+reg, col(expert)=lane&15 [m89] ----
  float bias[NT];
#pragma unroll
  for (int nt = 0; nt < NT; ++nt) bias[nt] = gb[nt * 16 + (lane & 15)];

  const int q = lane >> 4;
#pragma unroll
  for (int r = 0; r < 4; ++r) {
    float v1 = acch[0][r] + accl[0][r] + bias[0];
    int   i1 = lane & 15;
    float v2 = -3.402823466e+38f;
    int   i2 = i1;
#pragma unroll
    for (int nt = 1; nt < NT; ++nt) {
      const float v = acch[nt][r] + accl[nt][r] + bias[nt];
      const int  ie = nt * 16 + (lane & 15);
      if (v > v1)      { v2 = v1; i2 = i1; v1 = v; i1 = ie; }
      else if (v > v2) { v2 = v;  i2 = ie; }
    }
    // top-2 merge across the 16 lanes of this quarter
#pragma unroll
    for (int m = 1; m <= 8; m <<= 1) {
      const float o1 = __shfl_xor(v1, m, 64); const int oi1 = __shfl_xor(i1, m, 64);
      const float o2 = __shfl_xor(v2, m, 64); const int oi2 = __shfl_xor(i2, m, 64);
      const bool b = (o1 > v1) || (o1 == v1 && oi1 < i1);
      if (b) {
        const bool c = (v1 > o2) || (v1 == o2 && i1 < oi2);
        v2 = c ? v1 : o2; i2 = c ? i1 : oi2;
        v1 = o1; i1 = oi1;
      } else {
        const bool c = (o1 > v2) || (o1 == v2 && oi1 < i2);
        if (c) { v2 = o1; i2 = oi1; }
      }
    }
    if ((lane & 15) == 0) {
      const int tok = tok0 + q * 4 + r;
      const float e2 = expf(v2 - v1);
      const float s  = 1.f / (1.f + e2);
      out[2 * tok]     = s;                 // weights, descending like top_k
      out[2 * tok + 1] = e2 * s;
      out[2 * T + 2 * tok]     = (float)i1; // idx section (float-encoded)
      out[2 * T + 2 * tok + 1] = (float)i2;
    }
  }
}

// ---------------- fallback (proven R2 kernel) if ws too small ----------------
#define BK 64
#define NK4 (BK/4)
#define NCHUNK (HIDDEN/BK)
#define TPB 512
#define NWAVE 8
#define TPW 8
#define TPBK 64
typedef __attribute__((address_space(3))) unsigned int       lds_u32;
typedef __attribute__((address_space(1))) const unsigned int gbl_u32;

__global__ __launch_bounds__(TPB, 4)
void router_fb(const float* __restrict__ x, const float* __restrict__ Wg,
               const float* __restrict__ gb, float* __restrict__ out, int T)
{
  __shared__ float4 wlds[2][NK4][NEXP];
  __shared__ float4 xlds[2][NWAVE][TPW][NK4];
  const int tid = threadIdx.x, lane = tid & 63, wid = tid >> 6;
  const int tok0 = (int)blockIdx.x * TPBK + wid * TPW;
  float acc[TPW]; double dacc[TPW];
#pragma unroll
  for (int t = 0; t < TPW; ++t) { acc[t] = 0.f; dacc[t] = 0.0; }
  auto stageW = [&](int buf, int k0) {
#pragma unroll
    for (int j = 0; j < 2; ++j) {
      const int s = tid + j * TPB, e = s & 63, k4 = s >> 6;
      __builtin_amdgcn_global_load_lds((gbl_u32*)&Wg[(size_t)e * HIDDEN + k0 + 4 * k4],
                                       (lds_u32*)&wlds[buf][k4][e], 16, 0, 0);
    }
  };
  auto stageX = [&](int buf, int k0) {
#pragma unroll
    for (int j = 0; j < 2; ++j) {
      const int s = lane + j * 64, t = s >> 4, k4 = s & 15;
      __builtin_amdgcn_global_load_lds((gbl_u32*)&x[(size_t)(tok0 + t) * HIDDEN + k0 + 4 * k4],
                                       (lds_u32*)&xlds[buf][wid][t][k4], 16, 0, 0);
    }
  };
  stageW(0, 0); stageX(0, 0); __syncthreads();
  int cur = 0;
  for (int c = 0; c < NCHUNK; ++c) {
    if (c + 1 < NCHUNK) { stageW(cur ^ 1, (c + 1) * BK); stageX(cur ^ 1, (c + 1) * BK); }
#pragma unroll
    for (int k4 = 0; k4 < NK4; ++k4) {
      const float4 w = wlds[cur][k4][lane];
#pragma unroll
      for (int t = 0; t < TPW; ++t) {
        const float4 xv = xlds[cur][wid][t][k4];
        acc[t] = fmaf(xv.x, w.x, acc[t]); acc[t] = fmaf(xv.y, w.y, acc[t]);
        acc[t] = fmaf(xv.z, w.z, acc[t]); acc[t] = fmaf(xv.w, w.w, acc[t]);
      }
    }
#pragma unroll
    for (int t = 0; t < TPW; ++t) { dacc[t] += (double)acc[t]; acc[t] = 0.f; }
    __syncthreads(); cur ^= 1;
  }
  const float bv = gb[lane];
#pragma unroll
  for (int t = 0; t < TPW; ++t) {
    const float v = (float)dacc[t] + bv;
    float v1 = v; int i1 = lane;
#pragma unroll
    for (int off = 32; off >= 1; off >>= 1) {
      const float ov = __shfl_xor(v1, off, 64); const int oi = __shfl_xor(i1, off, 64);
      if (ov > v1 || (ov == v1 && oi < i1)) { v1 = ov; i1 = oi; }
    }
    float v2 = (lane == i1) ? -3.402823466e+38f : v; int i2 = lane;
#pragma unroll
    for (int off = 32; off >= 1; off >>= 1) {
      const float ov = __shfl_xor(v2, off, 64); const int oi = __shfl_xor(i2, off, 64);
      if (ov > v2 || (ov == v2 && oi < i2)) { v2 = ov; i2 = oi; }
    }
    if (lane == 0) {
      const int tok = tok0 + t;
      const float e2 = expf(v2 - v1), s = 1.f + e2;
      out[2 * tok] = 1.f / s; out[2 * tok + 1] = e2 / s;
      out[2 * T + 2 * tok] = (float)i1; out[2 * T + 2 * tok + 1] = (float)i2;
    }
  }
}

extern "C" void kernel_launch(void* const* d_in, const int* in_sizes, int n_in,
                              void* d_out, int out_size, void* d_ws, size_t ws_size,
                              hipStream_t stream) {
  const float* x  = (const float*)d_in[0];   // [4,8192,2048] f32
  const float* Wg = (const float*)d_in[1];   // [64,2048] f32
  const float* gb = (const float*)d_in[2];   // [64] f32
  float* out = (float*)d_out;
  const int T = in_sizes[0] / HIDDEN;        // 32768 tokens

  if (ws_size >= WS_HALVES * sizeof(_Float16)) {
    _Float16* ws = (_Float16*)d_ws;
    prep_w<<<dim3(64), dim3(256), 0, stream>>>(Wg, ws);
    router_mfma<<<dim3(T / 64), dim3(256), 0, stream>>>(x, ws, gb, out, T);
  } else {
    router_fb<<<dim3(T / TPBK), dim3(TPB), 0, stream>>>(x, Wg, gb, out, T);
  }
}

// Round 7
// 58.020 us; speedup vs baseline: 7.7114x; 1.4996x over previous
//
#include <hip/hip_runtime.h>
#include <math.h>

#define HIDDEN 2048
#define NEXP   64
#define KSTEPS (HIDDEN/32)    // 64 MFMA k-steps
#define NT     4              // four 16-expert N-tiles
#define CHUNK  4              // k-steps per LDS ws chunk
#define NCH    (KSTEPS/CHUNK) // 16
#define CH_HALVES (CHUNK*4096)  // 16384 halves = 32 KB per chunk
#define WS_HALVES (KSTEPS*NT*2*64*8)   // 262144 halves = 512 KB

typedef _Float16 f16x8 __attribute__((ext_vector_type(8)));
typedef float    f32x4 __attribute__((ext_vector_type(4)));
typedef __attribute__((address_space(3))) unsigned int       lds_u32;
typedef __attribute__((address_space(1))) const unsigned int gbl_u32;

// ---------------- prep: W -> split-f16 MFMA B-fragments in ws ----------------
// ws halves layout: ks*4096 + nt*1024 + split*512 + lane*8
// B-frag mapping (16x16x32): col(expert) = lane&15, k = 8*(lane>>4)+j
__global__ void prep_w(const float* __restrict__ Wg, _Float16* __restrict__ ws) {
  const int t    = blockIdx.x * 256 + threadIdx.x;  // 0..16383 = grp*64 + lane
  const int lane = t & 63;
  const int grp  = t >> 6;                          // ks*4 + nt
  const int e    = (grp & 3) * 16 + (lane & 15);
  const int k0   = (grp >> 2) * 32 + (lane >> 4) * 8;
  const float* src = &Wg[(size_t)e * HIDDEN + k0];
  f16x8 h, l;
#pragma unroll
  for (int j = 0; j < 8; ++j) {
    const float v = src[j];
    const _Float16 hh = (_Float16)v;        // RNE
    h[j] = hh;
    l[j] = (_Float16)(v - (float)hh);       // exact residual, RNE to f16
  }
  *(f16x8*)&ws[(size_t)grp * 1024 + 0   + lane * 8] = h;
  *(f16x8*)&ws[(size_t)grp * 1024 + 512 + lane * 8] = l;
}

// ---- main: split-f16 MFMA router; ws via block-shared LDS (lgkmcnt),
// ---- x via depth-4 register pipeline (vmcnt), counted-vmcnt barriers (T4).
__global__ __launch_bounds__(512, 2)   // 256-VGPR cap: no spill
void router_mfma(const float* __restrict__ x, const _Float16* __restrict__ ws,
                 const float* __restrict__ gb, float* __restrict__ out, int T)
{
  __shared__ _Float16 wt[2][CH_HALVES];   // 2 x 32 KB double-buffered ws chunk

  const int tid  = threadIdx.x;
  const int lane = tid & 63;
  const int tok0 = ((int)blockIdx.x * 8 + (tid >> 6)) * 16;   // 128 tok/block
  // A-frag: row(token) = lane&15, k = 8*(lane>>4)+j
  const float* xp = &x[(size_t)(tok0 + (lane & 15)) * HIDDEN + (lane >> 4) * 8];

  f32x4 acch[NT], accl[NT];
#pragma unroll
  for (int nt = 0; nt < NT; ++nt)
#pragma unroll
    for (int j = 0; j < 4; ++j) { acch[nt][j] = 0.f; accl[nt][j] = 0.f; }

  // stage one 4-kstep ws chunk into LDS (4 x gll16 per thread, lane-linear dest)
  auto stage = [&](int buf, int c) {
#pragma unroll
    for (int j = 0; j < 4; ++j) {
      const int s = j * 512 + tid;        // 0..2047 slots of 8 halves
      __builtin_amdgcn_global_load_lds(
          (gbl_u32*)(ws + (size_t)c * CH_HALVES + s * 8),
          (lds_u32*)(&wt[buf][s * 8]), 16, 0, 0);
    }
  };

  // ---- x prefetch pipeline, depth 4 (statically indexed via unroll) ----
  float4 pfa[4], pfb[4];
#pragma unroll
  for (int j = 0; j < 4; ++j) {
    pfa[j] = *(const float4*)(xp + j * 32);
    pfb[j] = *(const float4*)(xp + j * 32 + 4);
  }

  stage(0, 0);
  asm volatile("s_waitcnt vmcnt(0)" ::: "memory");   // prologue: full drain once
  __builtin_amdgcn_s_barrier();

  int cur = 0;
  for (int c = 0; c < NCH; ++c) {
    // issue next chunk's staging FIRST; pin issue order so the counted
    // vmcnt below drains exactly these 4 gll (and no x refill precedes them)
    if (c + 1 < NCH) stage(cur ^ 1, c + 1);
    __builtin_amdgcn_sched_barrier(0);

    const _Float16* wbase = &wt[cur][lane * 8];
#pragma unroll
    for (int j = 0; j < 4; ++j) {
      const int ks = c * CHUNK + j;

      // consume x slot j, refill it for ks+4 (stays in flight across barrier)
      const float4 xa = pfa[j], xb = pfb[j];
      if (ks + 4 < KSTEPS) {
        pfa[j] = *(const float4*)(xp + (ks + 4) * 32);
        pfb[j] = *(const float4*)(xp + (ks + 4) * 32 + 4);
      }

      // b-frags from LDS (lgkmcnt pipe; compiler schedules fine-grained waits)
      f16x8 bh[NT], bl[NT];
#pragma unroll
      for (int nt = 0; nt < NT; ++nt) {
        bh[nt] = *(const f16x8*)(wbase + j * 4096 + nt * 1024);
        bl[nt] = *(const f16x8*)(wbase + j * 4096 + nt * 1024 + 512);
      }

      // split x into hi/lo f16 (RNE, residual <= 2^-22) — proven R5 math
      const float xs[8] = {xa.x, xa.y, xa.z, xa.w, xb.x, xb.y, xb.z, xb.w};
      f16x8 ah, al;
#pragma unroll
      for (int q = 0; q < 8; ++q) {
        const _Float16 h = (_Float16)xs[q];
        ah[q] = h;
        al[q] = (_Float16)(xs[q] - (float)h);
      }

#pragma unroll
      for (int nt = 0; nt < NT; ++nt) {
        acch[nt] = __builtin_amdgcn_mfma_f32_16x16x32_f16(ah, bh[nt], acch[nt], 0, 0, 0);
        accl[nt] = __builtin_amdgcn_mfma_f32_16x16x32_f16(ah, bl[nt], accl[nt], 0, 0, 0);
        accl[nt] = __builtin_amdgcn_mfma_f32_16x16x32_f16(al, bh[nt], accl[nt], 0, 0, 0);
      }
    }

    // T4 counted boundary: keep the 8 newest (this chunk's x refills) in
    // flight; drain the 4 staging gll; order LDS reads; raw barrier.
    asm volatile("s_waitcnt vmcnt(8) lgkmcnt(0)" ::: "memory");
    __builtin_amdgcn_s_barrier();
    cur ^= 1;
  }

  // ---- epilogue: C/D row(token)=(lane>>4)*4+reg, col(expert)=lane&15 [m89] ----
  float bias[NT];
#pragma unroll
  for (int nt = 0; nt < NT; ++nt) bias[nt] = gb[nt * 16 + (lane & 15)];

  const int q = lane >> 4;
#pragma unroll
  for (int r = 0; r < 4; ++r) {
    float v1 = acch[0][r] + accl[0][r] + bias[0];
    int   i1 = lane & 15;
    float v2 = -3.402823466e+38f;
    int   i2 = i1;
#pragma unroll
    for (int nt = 1; nt < NT; ++nt) {
      const float v = acch[nt][r] + accl[nt][r] + bias[nt];
      const int  ie = nt * 16 + (lane & 15);
      if (v > v1)      { v2 = v1; i2 = i1; v1 = v; i1 = ie; }
      else if (v > v2) { v2 = v;  i2 = ie; }
    }
#pragma unroll
    for (int m = 1; m <= 8; m <<= 1) {
      const float o1 = __shfl_xor(v1, m, 64); const int oi1 = __shfl_xor(i1, m, 64);
      const float o2 = __shfl_xor(v2, m, 64); const int oi2 = __shfl_xor(i2, m, 64);
      const bool b = (o1 > v1) || (o1 == v1 && oi1 < i1);
      if (b) {
        const bool cnd = (v1 > o2) || (v1 == o2 && i1 < oi2);
        v2 = cnd ? v1 : o2; i2 = cnd ? i1 : oi2;
        v1 = o1; i1 = oi1;
      } else {
        const bool cnd = (o1 > v2) || (o1 == v2 && oi1 < i2);
        if (cnd) { v2 = o1; i2 = oi1; }
      }
    }
    if ((lane & 15) == 0) {
      const int tok = tok0 + q * 4 + r;
      const float e2 = expf(v2 - v1);
      const float s  = 1.f / (1.f + e2);
      out[2 * tok]     = s;                 // weights, descending like top_k
      out[2 * tok + 1] = e2 * s;
      out[2 * T + 2 * tok]     = (float)i1; // idx section (float-encoded)
      out[2 * T + 2 * tok + 1] = (float)i2;
    }
  }
}

// ---------------- fallback (proven R2 kernel) if ws too small ----------------
#define BK 64
#define NK4 (BK/4)
#define NCHUNK (HIDDEN/BK)
#define TPB 512
#define NWAVE 8
#define TPW 8
#define TPBK 64

__global__ __launch_bounds__(TPB, 4)
void router_fb(const float* __restrict__ x, const float* __restrict__ Wg,
               const float* __restrict__ gb, float* __restrict__ out, int T)
{
  __shared__ float4 wlds[2][NK4][NEXP];
  __shared__ float4 xlds[2][NWAVE][TPW][NK4];
  const int tid = threadIdx.x, lane = tid & 63, wid = tid >> 6;
  const int tok0 = (int)blockIdx.x * TPBK + wid * TPW;
  float acc[TPW]; double dacc[TPW];
#pragma unroll
  for (int t = 0; t < TPW; ++t) { acc[t] = 0.f; dacc[t] = 0.0; }
  auto stageW = [&](int buf, int k0) {
#pragma unroll
    for (int j = 0; j < 2; ++j) {
      const int s = tid + j * TPB, e = s & 63, k4 = s >> 6;
      __builtin_amdgcn_global_load_lds((gbl_u32*)&Wg[(size_t)e * HIDDEN + k0 + 4 * k4],
                                       (lds_u32*)&wlds[buf][k4][e], 16, 0, 0);
    }
  };
  auto stageX = [&](int buf, int k0) {
#pragma unroll
    for (int j = 0; j < 2; ++j) {
      const int s = lane + j * 64, t = s >> 4, k4 = s & 15;
      __builtin_amdgcn_global_load_lds((gbl_u32*)&x[(size_t)(tok0 + t) * HIDDEN + k0 + 4 * k4],
                                       (lds_u32*)&xlds[buf][wid][t][k4], 16, 0, 0);
    }
  };
  stageW(0, 0); stageX(0, 0); __syncthreads();
  int cur = 0;
  for (int c = 0; c < NCHUNK; ++c) {
    if (c + 1 < NCHUNK) { stageW(cur ^ 1, (c + 1) * BK); stageX(cur ^ 1, (c + 1) * BK); }
#pragma unroll
    for (int k4 = 0; k4 < NK4; ++k4) {
      const float4 w = wlds[cur][k4][lane];
#pragma unroll
      for (int t = 0; t < TPW; ++t) {
        const float4 xv = xlds[cur][wid][t][k4];
        acc[t] = fmaf(xv.x, w.x, acc[t]); acc[t] = fmaf(xv.y, w.y, acc[t]);
        acc[t] = fmaf(xv.z, w.z, acc[t]); acc[t] = fmaf(xv.w, w.w, acc[t]);
      }
    }
#pragma unroll
    for (int t = 0; t < TPW; ++t) { dacc[t] += (double)acc[t]; acc[t] = 0.f; }
    __syncthreads(); cur ^= 1;
  }
  const float bv = gb[lane];
#pragma unroll
  for (int t = 0; t < TPW; ++t) {
    const float v = (float)dacc[t] + bv;
    float v1 = v; int i1 = lane;
#pragma unroll
    for (int off = 32; off >= 1; off >>= 1) {
      const float ov = __shfl_xor(v1, off, 64); const int oi = __shfl_xor(i1, off, 64);
      if (ov > v1 || (ov == v1 && oi < i1)) { v1 = ov; i1 = oi; }
    }
    float v2 = (lane == i1) ? -3.402823466e+38f : v; int i2 = lane;
#pragma unroll
    for (int off = 32; off >= 1; off >>= 1) {
      const float ov = __shfl_xor(v2, off, 64); const int oi = __shfl_xor(i2, off, 64);
      if (ov > v2 || (ov == v2 && oi < i2)) { v2 = ov; i2 = oi; }
    }
    if (lane == 0) {
      const int tok = tok0 + t;
      const float e2 = expf(v2 - v1), s = 1.f + e2;
      out[2 * tok] = 1.f / s; out[2 * tok + 1] = e2 / s;
      out[2 * T + 2 * tok] = (float)i1; out[2 * T + 2 * tok + 1] = (float)i2;
    }
  }
}

extern "C" void kernel_launch(void* const* d_in, const int* in_sizes, int n_in,
                              void* d_out, int out_size, void* d_ws, size_t ws_size,
                              hipStream_t stream) {
  const float* x  = (const float*)d_in[0];   // [4,8192,2048] f32
  const float* Wg = (const float*)d_in[1];   // [64,2048] f32
  const float* gb = (const float*)d_in[2];   // [64] f32
  float* out = (float*)d_out;
  const int T = in_sizes[0] / HIDDEN;        // 32768 tokens

  if (ws_size >= WS_HALVES * sizeof(_Float16)) {
    _Float16* ws = (_Float16*)d_ws;
    prep_w<<<dim3(64), dim3(256), 0, stream>>>(Wg, ws);
    router_mfma<<<dim3(T / 128), dim3(512), 0, stream>>>(x, ws, gb, out, T);
  } else {
    router_fb<<<dim3(T / TPBK), dim3(TPB), 0, stream>>>(x, Wg, gb, out, T);
  }
}